// Round 3
// baseline (87.000 us; speedup 1.0000x reference)
//
#include <hip/hip_runtime.h>

// BlurredPhonemeEmbedding on MI355X (gfx950).
// B=32, T=8192, V=2820, D=64. Output (B,T,D) f32 = 64 MiB -> write-bound.
// Two-kernel split:
//   W: per 256-pos tile (+256 halo) ballot-based segment analysis -> (w, nb)
//      float2 per position into d_ws (2 MiB, L2-hot, normal stores).
//   G: pure streaming gather-blend, 8 float4/thread, register-prefetched
//      indices, nontemporal coalesced stores.

#define BFC    0.3f
#define TLEN   8192
#define TILE   256
#define HALO   256
#define SSTAGE (TILE + 2 * HALO)   // 768 staged positions
#define NWORD  (SSTAGE / 64)       // 12 bitmask words
#define NTH    256
#define DC     16                  // D/4 float4 per embedding row

typedef float f4 __attribute__((ext_vector_type(4)));

// Rare fallback paths (halo exhausted): scan global ids directly (L2-hot).
__device__ __forceinline__ int seg_start_global(const int* __restrict__ row, int t) {
    while (t > 0 && row[t] == row[t - 1]) --t;
    return t;
}
__device__ __forceinline__ int seg_end_global(const int* __restrict__ row, int t) {
    ++t;
    while (t < TLEN && row[t] == row[t - 1]) ++t;
    return t;
}

// largest set bit index <= li, or -1
__device__ __forceinline__ int bits_le(const unsigned long long* bm, int li) {
    int wi = li >> 6, bi = li & 63;
    unsigned long long m = bm[wi] & (~0ULL >> (63 - bi));
    while (m == 0ULL && wi > 0) m = bm[--wi];
    return m ? ((wi << 6) + 63 - __clzll((long long)m)) : -1;
}
// smallest set bit index > li, or -1
__device__ __forceinline__ int bits_gt(const unsigned long long* bm, int li) {
    int wi = li >> 6, bi = li & 63;
    unsigned long long m = (bi == 63) ? 0ULL : (bm[wi] & (~0ULL << (bi + 1)));
    while (m == 0ULL && wi < NWORD - 1) m = bm[++wi];
    return m ? ((wi << 6) + (__ffsll(m) - 1)) : -1;
}

// ---------------- Kernel W: weights + neighbor ids ----------------
__global__ __launch_bounds__(NTH) void blur_weights_kernel(
    const int* __restrict__ ids, float2* __restrict__ wn_out)
{
    __shared__ int sid[SSTAGE];
    __shared__ unsigned long long bmask[NWORD];

    const int b   = blockIdx.y;
    const int t0  = blockIdx.x * TILE;
    const int tid = threadIdx.x;
    const int* __restrict__ row = ids + (size_t)b * TLEN;

    #pragma unroll
    for (int k = 0; k < SSTAGE / NTH; ++k) {
        int i = tid + k * NTH;
        int t = t0 - HALO + i;
        sid[i] = (t >= 0 && t < TLEN) ? row[t] : 0;
    }
    __syncthreads();

    // boundary bitmask: bit set iff is_start(t). t>=T counts as virtual end.
    #pragma unroll
    for (int k = 0; k < SSTAGE / NTH; ++k) {
        int i = tid + k * NTH;
        int t = t0 - HALO + i;
        bool pred;
        if (t <= 0)         pred = (t == 0);
        else if (t >= TLEN) pred = true;
        else {
            int prv = (i >= 1) ? sid[i - 1] : row[t - 1];
            pred = (sid[i] != prv);
        }
        unsigned long long m = __ballot(pred);
        if ((tid & 63) == 0) bmask[i >> 6] = m;
    }
    __syncthreads();

    const int li = HALO + tid;
    const int t  = t0 + tid;
    int s_loc = bits_le(bmask, li);
    int e_loc = bits_gt(bmask, li);
    int start = (s_loc >= 0) ? (t0 - HALO + s_loc) : seg_start_global(row, t);
    int end   = (e_loc >= 0) ? (t0 - HALO + e_loc) : seg_end_global(row, t);
    int dur   = end - start;
    int myid  = sid[li];

    float w_n = 0.f, w_p = 0.f;
    int nid = myid, pid = myid;

    // right boundary (ramp toward next phoneme)
    if (end < TLEN) {
        int nxt_id, nend;
        if (e_loc >= 0) {
            nxt_id = sid[e_loc];
            int n_loc = bits_gt(bmask, e_loc);
            nend = (n_loc >= 0) ? (t0 - HALO + n_loc) : seg_end_global(row, end);
        } else {
            nxt_id = row[end];
            nend = seg_end_global(row, end);
        }
        float rad_n = BFC * (float)min(dur, nend - end);     // f32, matches jnp
        if (rad_n >= 0.5f) {
            int rn = max(1, (int)rintf(rad_n));              // round half-to-even
            int left_start = max(0, end - rn);
            if (t >= left_start) {
                w_n = fminf(0.5f * (float)(t - left_start + 1) / (float)rn, 0.5f);
                nid = nxt_id;
            }
        }
    }
    // left boundary (ramp from previous phoneme)
    if (start > 0) {
        int prv_id, pstart;
        if (s_loc >= 1) {
            prv_id = sid[s_loc - 1];
            int p_loc = bits_le(bmask, s_loc - 1);
            pstart = (p_loc >= 0) ? (t0 - HALO + p_loc) : seg_start_global(row, start - 1);
        } else {
            prv_id = row[start - 1];
            pstart = seg_start_global(row, start - 1);
        }
        float rad_p = BFC * (float)min(start - pstart, dur);
        if (rad_p >= 0.5f) {
            int rp = max(1, (int)rintf(rad_p));
            int right_end = min(TLEN, start + rp);
            if (t < right_end) {
                w_p = fminf(0.5f * (float)(right_end - t) / (float)rp, 0.5f);
                pid = prv_id;
            }
        }
    }
    float w = fmaxf(w_p, w_n);
    // ties (w_n == w_p) keep prev-boundary id, exactly like the reference
    int nb = (w_n > w_p) ? nid : ((w_p > 0.f) ? pid : myid);
    wn_out[(size_t)b * TLEN + t] = make_float2(w, __int_as_float(nb));
}

// ---------------- Kernel G: streaming gather-blend ----------------
// Total f4 elements: B*T*DC = 4,194,304. 2048 blocks x 256 thr x 8 f4/thr.
#define GBLK 2048
#define GITER 8
__global__ __launch_bounds__(NTH) void blur_gather_kernel(
    const int* __restrict__ ids, const float* __restrict__ table,
    const float2* __restrict__ wn, float* __restrict__ out)
{
    const f4* __restrict__ tbl4 = reinterpret_cast<const f4*>(table);
    f4* __restrict__ out4 = reinterpret_cast<f4*>(out);
    const int base = blockIdx.x * NTH + threadIdx.x;   // f4 index
    const int c = base & (DC - 1);                     // fixed chunk per thread

    // prefetch all indices/weights first (decouple from gathers -> MLP)
    float2 w8[GITER];
    int    id8[GITER];
    #pragma unroll
    for (int k = 0; k < GITER; ++k) {
        int p = (base + k * (GBLK * NTH)) >> 4;        // position
        w8[k]  = wn[p];
        id8[k] = ids[p];
    }
    #pragma unroll
    for (int k = 0; k < GITER; ++k) {
        int idx = base + k * (GBLK * NTH);
        int id = id8[k];
        int nb = __float_as_int(w8[k].y);
        float w = w8[k].x;
        f4 ea = tbl4[id * DC + c];
        f4 eb = tbl4[nb * DC + c];
        float wa = (id != 0) ? (1.0f - w) : 0.0f;      // padding_idx guard
        float wb = (nb != 0) ? w : 0.0f;
        f4 o = ea * wa + eb * wb;
        __builtin_nontemporal_store(o, &out4[idx]);
    }
}

extern "C" void kernel_launch(void* const* d_in, const int* in_sizes, int n_in,
                              void* d_out, int out_size, void* d_ws, size_t ws_size,
                              hipStream_t stream) {
    const int*   ids   = (const int*)d_in[0];    // (B,T) int32
    const float* table = (const float*)d_in[1];  // (V,D) f32
    float*       out   = (float*)d_out;          // (B,T,D) f32
    float2*      wn    = (float2*)d_ws;          // (B,T) packed (w, neighbor)

    const int n_ids = in_sizes[0];               // B*T
    const int B = n_ids / TLEN;                  // 32

    dim3 gridW(TLEN / TILE, B);                  // 1024 blocks
    blur_weights_kernel<<<gridW, NTH, 0, stream>>>(ids, wn);
    blur_gather_kernel<<<GBLK, NTH, 0, stream>>>(ids, table, wn, out);
}

// Round 4
// 82.545 us; speedup vs baseline: 1.0540x; 1.0540x over previous
//
#include <hip/hip_runtime.h>

// BlurredPhonemeEmbedding on MI355X (gfx950).
// B=32, T=8192, V=2820, D=64. Output (B,T,D) f32 = 64 MiB -> write-bound.
// Wave-autonomous fused kernel: each 64-lane wave owns a 64-position tile
// with a 320-id window (+-128 halo) in a private LDS slice. Boundary bitmask
// built via __ballot during staging (shfl_up + carry). ZERO block barriers:
// weight compute + gather-blend read only same-wave LDS, so waves free-run
// and latency-bound analysis overlaps other waves' streaming stores.

#define BFC     0.3f
#define TLEN    8192
#define WTILE   64                  // positions per wave
#define WHALO   128
#define WWIN    (WTILE + 2 * WHALO) // 320 staged ids per wave
#define WROUNDS (WWIN / 64)         // 5 ballot words
#define NTH     256
#define NWAVE   (NTH / 64)
#define DC      16                  // D/4 float4 per embedding row

typedef float f4 __attribute__((ext_vector_type(4)));

// Rare fallback paths (halo exhausted; P ~ 0.85^128 per segment): global scan.
__device__ __forceinline__ int seg_start_global(const int* __restrict__ row, int t) {
    while (t > 0 && row[t] == row[t - 1]) --t;
    return t;
}
__device__ __forceinline__ int seg_end_global(const int* __restrict__ row, int t) {
    ++t;
    while (t < TLEN && row[t] == row[t - 1]) ++t;
    return t;
}

// largest set bit index <= li, or -1 (5-word window)
__device__ __forceinline__ int bits_le(const unsigned long long* bm, int li) {
    int wi = li >> 6, bi = li & 63;
    unsigned long long m = bm[wi] & (~0ULL >> (63 - bi));
    while (m == 0ULL && wi > 0) m = bm[--wi];
    return m ? ((wi << 6) + 63 - __clzll((long long)m)) : -1;
}
// smallest set bit index > li, or -1
__device__ __forceinline__ int bits_gt(const unsigned long long* bm, int li) {
    int wi = li >> 6, bi = li & 63;
    unsigned long long m = (bi == 63) ? 0ULL : (bm[wi] & (~0ULL << (bi + 1)));
    while (m == 0ULL && wi < WROUNDS - 1) m = bm[++wi];
    return m ? ((wi << 6) + (__ffsll(m) - 1)) : -1;
}

__global__ __launch_bounds__(NTH) void blur_phoneme_kernel(
    const int* __restrict__ ids, const float* __restrict__ table,
    float* __restrict__ out)
{
    __shared__ int                sid_all[NWAVE][WWIN];
    __shared__ unsigned long long bm_all[NWAVE][WROUNDS];
    __shared__ float2             wn_all[NWAVE][WTILE];

    const int b    = blockIdx.y;
    const int wave = threadIdx.x >> 6;
    const int lane = threadIdx.x & 63;
    const int t0w  = blockIdx.x * NTH + wave * WTILE;   // this wave's 64 positions
    const int* __restrict__ row = ids + (size_t)b * TLEN;

    int*                sid = sid_all[wave];
    unsigned long long* bm  = bm_all[wave];
    float2*             wn  = wn_all[wave];

    // ---- stage window + build boundary bitmask in one pass ----
    // bit i set iff is_start(first+i); t==0 and t>=TLEN are walls.
    const int first = t0w - WHALO;
    int carry = (first > 0) ? row[first - 1] : 0;       // uniform broadcast load
    #pragma unroll
    for (int r = 0; r < WROUNDS; ++r) {
        int i = r * 64 + lane;
        int t = first + i;
        int id = (t >= 0 && t < TLEN) ? row[t] : 0;
        sid[i] = id;
        int prv = __shfl_up(id, 1);
        if (lane == 0) prv = carry;
        bool pred = (t <= 0) ? (t == 0) : ((t >= TLEN) ? true : (id != prv));
        unsigned long long m = __ballot(pred);
        if (lane == 0) bm[r] = m;
        carry = __shfl(id, 63);
    }
    __builtin_amdgcn_wave_barrier();

    // ---- per-position weight + neighbor (lane = position offset) ----
    {
        const int li = WHALO + lane;
        const int t  = t0w + lane;
        int s_loc = bits_le(bm, li);
        int e_loc = bits_gt(bm, li);
        int start = (s_loc >= 0) ? (first + s_loc) : seg_start_global(row, t);
        int end   = (e_loc >= 0) ? (first + e_loc) : seg_end_global(row, t);
        int dur   = end - start;
        int myid  = sid[li];

        float w_n = 0.f, w_p = 0.f;
        int nid = myid, pid = myid;

        // right boundary (ramp toward next phoneme)
        if (end < TLEN) {
            int nxt_id, nend;
            if (e_loc >= 0) {
                nxt_id = sid[e_loc];
                int n_loc = bits_gt(bm, e_loc);
                nend = (n_loc >= 0) ? (first + n_loc) : seg_end_global(row, end);
            } else {
                nxt_id = row[end];
                nend = seg_end_global(row, end);
            }
            float rad_n = BFC * (float)min(dur, nend - end);     // f32, matches jnp
            if (rad_n >= 0.5f) {
                int rn = max(1, (int)rintf(rad_n));              // round half-to-even
                int left_start = max(0, end - rn);
                if (t >= left_start) {
                    w_n = fminf(0.5f * (float)(t - left_start + 1) / (float)rn, 0.5f);
                    nid = nxt_id;
                }
            }
        }
        // left boundary (ramp from previous phoneme)
        if (start > 0) {
            int prv_id, pstart;
            if (s_loc >= 1) {
                prv_id = sid[s_loc - 1];
                int p_loc = bits_le(bm, s_loc - 1);
                pstart = (p_loc >= 0) ? (first + p_loc) : seg_start_global(row, start - 1);
            } else {
                prv_id = row[start - 1];
                pstart = seg_start_global(row, start - 1);
            }
            float rad_p = BFC * (float)min(start - pstart, dur);
            if (rad_p >= 0.5f) {
                int rp = max(1, (int)rintf(rad_p));
                int right_end = min(TLEN, start + rp);
                if (t < right_end) {
                    w_p = fminf(0.5f * (float)(right_end - t) / (float)rp, 0.5f);
                    pid = prv_id;
                }
            }
        }
        float w = fmaxf(w_p, w_n);
        // ties (w_n == w_p) keep prev-boundary id, exactly like the reference
        int nb = (w_n > w_p) ? nid : ((w_p > 0.f) ? pid : myid);
        wn[lane] = make_float2(w, __int_as_float(nb));
    }
    __builtin_amdgcn_wave_barrier();

    // ---- gather + blend + coalesced nontemporal float4 store ----
    // iter k: wave stores positions 4k..4k+3 (1 KiB contiguous).
    const f4* __restrict__ tbl4 = reinterpret_cast<const f4*>(table);
    f4* __restrict__ out4 = reinterpret_cast<f4*>(out) + ((size_t)b * TLEN + t0w) * DC;
    const int c    = lane & (DC - 1);
    const int psub = lane >> 4;
    #pragma unroll
    for (int k = 0; k < WTILE * DC / 64; ++k) {          // 16 iters
        int p = 4 * k + psub;
        int id = sid[WHALO + p];
        float2 w2 = wn[p];
        int nb = __float_as_int(w2.y);
        float w = w2.x;
        f4 ea = tbl4[id * DC + c];
        f4 eb = tbl4[nb * DC + c];
        float wa = (id != 0) ? (1.0f - w) : 0.0f;        // padding_idx guard
        float wb = (nb != 0) ? w : 0.0f;
        f4 o = ea * wa + eb * wb;
        __builtin_nontemporal_store(o, &out4[k * 64 + lane]);
    }
}

extern "C" void kernel_launch(void* const* d_in, const int* in_sizes, int n_in,
                              void* d_out, int out_size, void* d_ws, size_t ws_size,
                              hipStream_t stream) {
    const int*   ids   = (const int*)d_in[0];    // (B,T) int32
    const float* table = (const float*)d_in[1];  // (V,D) f32
    float*       out   = (float*)d_out;          // (B,T,D) f32

    const int n_ids = in_sizes[0];               // B*T
    const int B = n_ids / TLEN;                  // 32

    dim3 grid(TLEN / NTH, B);                    // (32, 32) = 1024 blocks, 4 waves each
    blur_phoneme_kernel<<<grid, NTH, 0, stream>>>(ids, table, out);
}